// Round 1
// baseline (463.059 us; speedup 1.0000x reference)
//
#include <hip/hip_runtime.h>

#define Cc  256
#define Hh  96
#define Ww  96
#define HW  (Hh*Ww)          // 9216
#define OC  32
#define HS  192
#define WSS 192
#define PLANE (HS*WSS)       // 36864

// Kernel 1: 1x1 conv (C=256 -> 32) + pixel_shuffle(2) + tanh + grid build.
// Restructured for occupancy: 256 threads = 4 waves per block, 64 pixels per
// block. Each wave reduces a 64-channel slice for all 64 pixels; partials are
// combined through LDS (reusing the weight buffer). 1152 blocks x 4 waves
// = 4608 waves (~4.5/SIMD) vs the old 1152 waves (~1.1/SIMD).
__global__ __launch_bounds__(256) void conv_offset_kernel(
    const float* __restrict__ x, const float* __restrict__ w,
    const float* __restrict__ bias, float* __restrict__ grid_buf)
{
    __shared__ float lds[Cc * OC];   // 32 KB: weights (phase 1), partials (phase 2)
    const int tid   = threadIdx.x;
    const int pix   = tid & 63;      // lane  -> pixel (coalesced loads)
    const int slice = tid >> 6;      // wave  -> 64-channel slice

    // stage transposed weights: lds[c*32 + o] = w[o*256 + c]
    for (int l = tid; l < Cc * OC; l += 256) {
        int cc = l >> 5, oo = l & 31;
        lds[l] = w[oo * Cc + cc];
    }
    __syncthreads();

    const int p  = blockIdx.x * 64 + pix;   // 73728 pixels, 1152 blocks exactly
    const int b  = p / HW;                  // HW % 64 == 0: no b-split inside block
    const int hw = p - b * HW;
    const float* xp = x + (size_t)b * Cc * HW + (size_t)(slice * 64) * HW + hw;

    float acc[OC];
    #pragma unroll
    for (int o = 0; o < OC; ++o) acc[o] = 0.0f;

    const float* wrow = &lds[slice * 64 * OC];
    #pragma unroll 4
    for (int c = 0; c < 64; ++c) {
        float xv = xp[(size_t)c * HW];                  // coalesced across lanes
        const float4* wr4 = (const float4*)&wrow[c * OC]; // broadcast ds_read_b128
        #pragma unroll
        for (int o4 = 0; o4 < 8; ++o4) {
            float4 wv = wr4[o4];
            acc[4*o4+0] = fmaf(wv.x, xv, acc[4*o4+0]);
            acc[4*o4+1] = fmaf(wv.y, xv, acc[4*o4+1]);
            acc[4*o4+2] = fmaf(wv.z, xv, acc[4*o4+2]);
            acc[4*o4+3] = fmaf(wv.w, xv, acc[4*o4+3]);
        }
    }

    __syncthreads();   // weights dead from here; reuse lds for partials
    // partial layout: lds[(o*4 + slice)*64 + pix] -- stride-1 across lanes
    #pragma unroll
    for (int o = 0; o < OC; ++o) lds[(o * 4 + slice) * 64 + pix] = acc[o];
    __syncthreads();

    // each thread finishes 8 outputs: its pixel, o in [slice*8, slice*8+8)
    const int h  = hw / Ww;
    const int ww = hw - h * Ww;
    const int obase = slice * 8;
    #pragma unroll
    for (int oo = 0; oo < 8; ++oo) {
        const int o = obase + oo;
        float s = lds[(o * 4 + 0) * 64 + pix]
                + lds[(o * 4 + 1) * 64 + pix]
                + lds[(o * 4 + 2) * 64 + pix]
                + lds[(o * 4 + 3) * 64 + pix] + bias[o];
        // o = co*4 + i*2 + j ; co = gr*2 + k (k: 0 = x-coord, 1 = y-coord)
        const int co  = o >> 2;
        const int rem = o & 3;
        const int i   = rem >> 1;
        const int j   = rem & 1;
        const int gr  = co >> 1;
        const int k   = co & 1;
        const int hs  = 2 * h + i;
        const int ws  = 2 * ww + j;
        float t = tanhf(s);
        // absolute source coord: (grid_norm + 1)*48 - 0.5
        float coord = (k == 0) ? (0.5f * (float)ws - 0.25f + 6.0f * t)
                               : (0.5f * (float)hs - 0.25f + 6.0f * t);
        coord = fminf(fmaxf(coord, 0.0f), 95.0f);   // border clamp
        const int bg = b * 4 + gr;
        grid_buf[(((size_t)bg * HS + hs) * WSS + ws) * 2 + k] = coord;
    }
}

// Kernel 2: bilinear gather with the full source plane staged in LDS.
// One block per (b,c) plane; 256 threads x 144 outputs each. (unchanged)
__global__ __launch_bounds__(256) void sample_kernel(
    const float* __restrict__ x, const float* __restrict__ grid_buf,
    float* __restrict__ out)
{
    __shared__ float pl[9344];           // 9216 plane + 128 pad (border taps ×0)
    const int bc  = blockIdx.x;          // b*256 + c
    const int b   = bc >> 8;
    const int c   = bc & 255;
    const int bg  = b * 4 + (c >> 6);
    const int tid = threadIdx.x;

    // stage plane: 2304 float4, coalesced, x read exactly once from HBM total
    const float4* xp4 = (const float4*)(x + (size_t)bc * HW);
    float4* pl4 = (float4*)pl;
    #pragma unroll
    for (int i = 0; i < 9; ++i) pl4[tid + 256 * i] = xp4[tid + 256 * i];
    if (tid < 128) pl[9216 + tid] = 0.0f;   // pad: out-of-range taps read 0 (weight 0)
    __syncthreads();

    const float* gbase = grid_buf + (size_t)bg * PLANE * 2;
    float* obase = out + (size_t)bc * PLANE;

    for (int r = 0; r < 36; ++r) {
        const int idx = r * 1024 + tid * 4;        // linear output idx in plane, %4==0
        const float4* gp = (const float4*)(gbase + (size_t)idx * 2); // 32B aligned
        float4 g01 = gp[0];   // gx0,gy0,gx1,gy1
        float4 g23 = gp[1];   // gx2,gy2,gx3,gy3
        float gx[4] = {g01.x, g01.z, g23.x, g23.z};
        float gy[4] = {g01.y, g01.w, g23.y, g23.w};
        float res[4];
        #pragma unroll
        for (int q = 0; q < 4; ++q) {
            float fx = gx[q], fy = gy[q];
            float x0f = floorf(fx), y0f = floorf(fy);
            float wx = fx - x0f, wy = fy - y0f;
            int base = (int)fmaf(y0f, 96.0f, x0f);  // exact int in fp32 range
            float a0 = pl[base],      a1 = pl[base + 1];   // ds_read2_b32
            float b0 = pl[base + 96], b1 = pl[base + 97];  // ds_read2_b32
            float top = a0 + (a1 - a0) * wx;
            float bot = b0 + (b1 - b0) * wx;
            res[q] = top + (bot - top) * wy;
        }
        *(float4*)(obase + idx) = make_float4(res[0], res[1], res[2], res[3]);
    }
}

extern "C" void kernel_launch(void* const* d_in, const int* in_sizes, int n_in,
                              void* d_out, int out_size, void* d_ws, size_t ws_size,
                              hipStream_t stream) {
    const float* x    = (const float*)d_in[0];
    const float* w    = (const float*)d_in[1];
    const float* bias = (const float*)d_in[2];
    float* out        = (float*)d_out;
    float* grid_buf   = (float*)d_ws;   // 32*192*192*2 floats = 9.4 MB

    conv_offset_kernel<<<1152, 256, 0, stream>>>(x, w, bias, grid_buf);
    sample_kernel<<<2048, 256, 0, stream>>>(x, grid_buf, out);
}

// Round 2
// 388.800 us; speedup vs baseline: 1.1910x; 1.1910x over previous
//
#include <hip/hip_runtime.h>

#define Cc  256
#define Hh  96
#define Ww  96
#define HW  (Hh*Ww)          // 9216
#define OC  32
#define HS  192
#define WSS 192
#define PLANE (HS*WSS)       // 36864
#define WT_FLOATS (Cc*OC)    // 8192

// Kernel 0: transpose w [32][256] -> wt [256][32] so K1 can s_load contiguous
// 128B rows of weights into SGPRs. 8192 floats, ~2 us.
__global__ __launch_bounds__(256) void transpose_w_kernel(
    const float* __restrict__ w, float* __restrict__ wt)
{
    const int l = blockIdx.x * 256 + threadIdx.x;   // 8192 exactly
    const int o = l >> 8, c = l & 255;
    wt[c * OC + o] = w[l];
}

// Kernel 1: 1x1 conv (C=256 -> 32) + pixel_shuffle(2) + tanh + grid build.
// 4 waves/block = 4 x 64-channel slices over the same 64 pixels; partials
// reduced through LDS. Weights now come from the transposed wt[] via
// wave-uniform indices -> compiler emits s_load + v_fmac with SGPR operand:
// ZERO ds_read in the inner loop (was 512 ds_read_b128/wave, ~31 us of
// DS-pipe time across the kernel).
__global__ __launch_bounds__(256) void conv_offset_kernel(
    const float* __restrict__ x, const float* __restrict__ wt,
    const float* __restrict__ bias, float* __restrict__ grid_buf)
{
    __shared__ float lds[Cc * OC];   // 32 KB, partials only
    const int tid   = threadIdx.x;
    const int pix   = tid & 63;      // lane  -> pixel (coalesced loads)
    const int slice = __builtin_amdgcn_readfirstlane(threadIdx.x >> 6); // wave-uniform

    const int p  = blockIdx.x * 64 + pix;   // 73728 pixels, 1152 blocks exactly
    const int b  = p / HW;                  // HW % 64 == 0: no b-split inside block
    const int hw = p - b * HW;
    const float* xp = x + (size_t)b * Cc * HW + (size_t)(slice * 64) * HW + hw;
    const float* wp = wt + slice * (64 * OC);   // wave-uniform base

    float acc[OC];
    #pragma unroll
    for (int o = 0; o < OC; ++o) acc[o] = 0.0f;

    #pragma unroll 4
    for (int c = 0; c < 64; ++c) {
        float xv = xp[(size_t)c * HW];              // coalesced across lanes
        const float4* w4 = (const float4*)&wp[c * OC];  // uniform -> s_load
        #pragma unroll
        for (int o4 = 0; o4 < 8; ++o4) {
            float4 wv = w4[o4];
            acc[4*o4+0] = fmaf(wv.x, xv, acc[4*o4+0]);
            acc[4*o4+1] = fmaf(wv.y, xv, acc[4*o4+1]);
            acc[4*o4+2] = fmaf(wv.z, xv, acc[4*o4+2]);
            acc[4*o4+3] = fmaf(wv.w, xv, acc[4*o4+3]);
        }
    }

    // partial layout: lds[(o*4 + slice)*64 + pix] -- stride-1 across lanes
    #pragma unroll
    for (int o = 0; o < OC; ++o) lds[(o * 4 + slice) * 64 + pix] = acc[o];
    __syncthreads();

    // each thread finishes 8 outputs: its pixel, o in [slice*8, slice*8+8)
    const int h  = hw / Ww;
    const int ww = hw - h * Ww;
    const int obase = slice * 8;
    #pragma unroll
    for (int oo = 0; oo < 8; ++oo) {
        const int o = obase + oo;
        float s = lds[(o * 4 + 0) * 64 + pix]
                + lds[(o * 4 + 1) * 64 + pix]
                + lds[(o * 4 + 2) * 64 + pix]
                + lds[(o * 4 + 3) * 64 + pix] + bias[o];
        // o = co*4 + i*2 + j ; co = gr*2 + k (k: 0 = x-coord, 1 = y-coord)
        const int co  = o >> 2;
        const int rem = o & 3;
        const int i   = rem >> 1;
        const int j   = rem & 1;
        const int gr  = co >> 1;
        const int k   = co & 1;
        const int hs  = 2 * h + i;
        const int ws  = 2 * ww + j;
        float t = tanhf(s);
        // absolute source coord: (grid_norm + 1)*48 - 0.5
        float coord = (k == 0) ? (0.5f * (float)ws - 0.25f + 6.0f * t)
                               : (0.5f * (float)hs - 0.25f + 6.0f * t);
        coord = fminf(fmaxf(coord, 0.0f), 95.0f);   // border clamp
        const int bg = b * 4 + gr;
        grid_buf[(((size_t)bg * HS + hs) * WSS + ws) * 2 + k] = coord;
    }
}

// Kernel 2: bilinear gather, TWO channels of the same group per block with
// the planes interleaved as float2 in LDS. One ds_read2_b64 fetches a tap
// pair for BOTH channels -> DS instrs, coord VALU and grid L2 traffic all
// halve per output. 512 threads, 74.7 KB LDS -> 2 blocks/CU = 16 waves/CU.
__global__ __launch_bounds__(512) void sample_kernel(
    const float* __restrict__ x, const float* __restrict__ grid_buf,
    float* __restrict__ out)
{
    __shared__ __align__(16) float2 pl[9344];   // 9216 interleaved + 128 pad
    const int bp  = blockIdx.x;          // b*128 + (c>>1)
    const int b   = bp >> 7;
    const int c2  = (bp & 127) << 1;     // channels c2, c2+1 (same group)
    const int bg  = b * 4 + (c2 >> 6);
    const int tid = threadIdx.x;

    // stage both planes interleaved: pl[i] = {x_c0[i], x_c1[i]}
    const float4* xp0 = (const float4*)(x + (size_t)(b * 256 + c2) * HW);
    const float4* xp1 = (const float4*)(x + (size_t)(b * 256 + c2 + 1) * HW);
    float4* pl4 = (float4*)pl;
    #pragma unroll
    for (int i = 0; i < 5; ++i) {
        int t = tid + 512 * i;                 // 2304 float4 per plane
        if (i < 4 || t < 2304) {
            float4 a = xp0[t];
            float4 bb = xp1[t];
            pl4[2 * t]     = make_float4(a.x, bb.x, a.y, bb.y);
            pl4[2 * t + 1] = make_float4(a.z, bb.z, a.w, bb.w);
        }
    }
    if (tid < 128) pl[9216 + tid] = make_float2(0.0f, 0.0f);  // border pad
    __syncthreads();

    const float* gbase = grid_buf + (size_t)bg * PLANE * 2;
    float* ob0 = out + (size_t)(b * 256 + c2) * PLANE;
    float* ob1 = ob0 + PLANE;

    #pragma unroll 2
    for (int r = 0; r < 72; ++r) {
        const int idx = r * 512 + tid;         // stride-1 across lanes
        float2 g = *(const float2*)(gbase + (size_t)idx * 2);  // coalesced 8B
        float x0f = floorf(g.x), y0f = floorf(g.y);
        float wx = g.x - x0f, wy = g.y - y0f;
        int base = (int)fmaf(y0f, 96.0f, x0f);  // exact int in fp32 range
        float2 a0 = pl[base],      a1 = pl[base + 1];    // ds_read2_b64
        float2 b0 = pl[base + 96], b1 = pl[base + 97];   // ds_read2_b64
        // channel c2
        float top0 = a0.x + (a1.x - a0.x) * wx;
        float bot0 = b0.x + (b1.x - b0.x) * wx;
        ob0[idx] = top0 + (bot0 - top0) * wy;
        // channel c2+1
        float top1 = a0.y + (a1.y - a0.y) * wx;
        float bot1 = b0.y + (b1.y - b0.y) * wx;
        ob1[idx] = top1 + (bot1 - top1) * wy;
    }
}

extern "C" void kernel_launch(void* const* d_in, const int* in_sizes, int n_in,
                              void* d_out, int out_size, void* d_ws, size_t ws_size,
                              hipStream_t stream) {
    const float* x    = (const float*)d_in[0];
    const float* w    = (const float*)d_in[1];
    const float* bias = (const float*)d_in[2];
    float* out        = (float*)d_out;
    float* wt         = (float*)d_ws;                 // 32 KB transposed weights
    float* grid_buf   = wt + WT_FLOATS;               // 9.4 MB grid coords

    transpose_w_kernel<<<32, 256, 0, stream>>>(w, wt);
    conv_offset_kernel<<<1152, 256, 0, stream>>>(x, wt, bias, grid_buf);
    sample_kernel<<<1024, 512, 0, stream>>>(x, grid_buf, out);
}

// Round 4
// 382.164 us; speedup vs baseline: 1.2117x; 1.0174x over previous
//
#include <hip/hip_runtime.h>

#define Cc  256
#define Hh  96
#define Ww  96
#define HW  (Hh*Ww)          // 9216
#define OC  32
#define HS  192
#define WSS 192
#define PLANE (HS*WSS)       // 36864
#define WT_FLOATS (Cc*OC)    // 8192

typedef float f32x2 __attribute__((ext_vector_type(2)));

// Kernel 0: transpose w [32][256] -> wt [256][32] so K1 can s_load contiguous
// 128B rows of weights into SGPRs. 8192 floats, ~2 us.
__global__ __launch_bounds__(256) void transpose_w_kernel(
    const float* __restrict__ w, float* __restrict__ wt)
{
    const int l = blockIdx.x * 256 + threadIdx.x;   // 8192 exactly
    const int o = l >> 8, c = l & 255;
    wt[c * OC + o] = w[l];
}

// Kernel 1: 1x1 conv (C=256 -> 32) + pixel_shuffle(2) + tanh + grid build.
// 4 waves/block = 4 x 64-channel slices over the same 64 pixels; partials
// reduced through LDS. Weights come from transposed wt[] via wave-uniform
// indices -> s_load + v_fmac with SGPR operand (zero ds_read in inner loop).
// unroll 8: more strided x loads in flight (load-latency-limited at
// ~4.5 waves/SIMD).
__global__ __launch_bounds__(256) void conv_offset_kernel(
    const float* __restrict__ x, const float* __restrict__ wt,
    const float* __restrict__ bias, float* __restrict__ grid_buf)
{
    __shared__ float lds[Cc * OC];   // 32 KB, partials only
    const int tid   = threadIdx.x;
    const int pix   = tid & 63;      // lane  -> pixel (coalesced loads)
    const int slice = __builtin_amdgcn_readfirstlane(threadIdx.x >> 6); // wave-uniform

    const int p  = blockIdx.x * 64 + pix;   // 73728 pixels, 1152 blocks exactly
    const int b  = p / HW;                  // HW % 64 == 0: no b-split inside block
    const int hw = p - b * HW;
    const float* xp = x + (size_t)b * Cc * HW + (size_t)(slice * 64) * HW + hw;
    const float* wp = wt + slice * (64 * OC);   // wave-uniform base

    float acc[OC];
    #pragma unroll
    for (int o = 0; o < OC; ++o) acc[o] = 0.0f;

    #pragma unroll 8
    for (int c = 0; c < 64; ++c) {
        float xv = xp[(size_t)c * HW];              // coalesced across lanes
        const float4* w4 = (const float4*)&wp[c * OC];  // uniform -> s_load
        #pragma unroll
        for (int o4 = 0; o4 < 8; ++o4) {
            float4 wv = w4[o4];
            acc[4*o4+0] = fmaf(wv.x, xv, acc[4*o4+0]);
            acc[4*o4+1] = fmaf(wv.y, xv, acc[4*o4+1]);
            acc[4*o4+2] = fmaf(wv.z, xv, acc[4*o4+2]);
            acc[4*o4+3] = fmaf(wv.w, xv, acc[4*o4+3]);
        }
    }

    // partial layout: lds[(o*4 + slice)*64 + pix] -- stride-1 across lanes
    #pragma unroll
    for (int o = 0; o < OC; ++o) lds[(o * 4 + slice) * 64 + pix] = acc[o];
    __syncthreads();

    // each thread finishes 8 outputs: its pixel, o in [slice*8, slice*8+8)
    const int h  = hw / Ww;
    const int ww = hw - h * Ww;
    const int obase = slice * 8;
    #pragma unroll
    for (int oo = 0; oo < 8; ++oo) {
        const int o = obase + oo;
        float s = lds[(o * 4 + 0) * 64 + pix]
                + lds[(o * 4 + 1) * 64 + pix]
                + lds[(o * 4 + 2) * 64 + pix]
                + lds[(o * 4 + 3) * 64 + pix] + bias[o];
        // o = co*4 + i*2 + j ; co = gr*2 + k (k: 0 = x-coord, 1 = y-coord)
        const int co  = o >> 2;
        const int rem = o & 3;
        const int i   = rem >> 1;
        const int j   = rem & 1;
        const int gr  = co >> 1;
        const int k   = co & 1;
        const int hs  = 2 * h + i;
        const int ws  = 2 * ww + j;
        float t = tanhf(s);
        // absolute source coord: (grid_norm + 1)*48 - 0.5
        float coord = (k == 0) ? (0.5f * (float)ws - 0.25f + 6.0f * t)
                               : (0.5f * (float)hs - 0.25f + 6.0f * t);
        coord = fminf(fmaxf(coord, 0.0f), 95.0f);   // border clamp
        const int bg = b * 4 + gr;
        grid_buf[(((size_t)bg * HS + hs) * WSS + ws) * 2 + k] = coord;
    }
}

// Kernel 2: bilinear gather, FOUR channels of the same group per block with
// the planes interleaved as float4 in LDS (149.5 KB -> 1 block/CU, 1024
// threads = 16 waves/CU, same occupancy as before). Each lane handles 2
// consecutive output positions x 4 channels per iteration:
//  - one float4 grid load per 8 outputs (grid L2 traffic /4 vs pair version)
//  - tap ds_read_b128 at 16B lane stride (conflict-free minimum pattern)
//  - f32x2 nontemporal stores (0.5 store-instr/output, no L2 pollution)
// Staging: lane u writes pl[u] (16B stride, conflict-free) from 4 coalesced
// 4B nontemporal load streams.
__global__ __launch_bounds__(1024) void sample_kernel(
    const float* __restrict__ x, const float* __restrict__ grid_buf,
    float* __restrict__ out)
{
    __shared__ __align__(16) float4 pl[9344];   // 9216 interleaved + 128 pad
    const int bq  = blockIdx.x;          // b*64 + (c>>2)
    const int b   = bq >> 6;
    const int c4  = (bq & 63) << 2;      // channels c4..c4+3 (same group)
    const int bg  = b * 4 + (c4 >> 6);
    const int tid = threadIdx.x;

    const float* x0 = x + (size_t)(b * 256 + c4) * HW;
    #pragma unroll
    for (int i = 0; i < 9; ++i) {
        int t = tid + 1024 * i;                    // 9216 exactly
        float a = __builtin_nontemporal_load(x0 + t);
        float bb = __builtin_nontemporal_load(x0 + HW + t);
        float cc = __builtin_nontemporal_load(x0 + 2 * HW + t);
        float dd = __builtin_nontemporal_load(x0 + 3 * HW + t);
        pl[t] = make_float4(a, bb, cc, dd);        // 16B lane stride: no conflict
    }
    if (tid < 128) pl[9216 + tid] = make_float4(0.f, 0.f, 0.f, 0.f); // border pad
    __syncthreads();

    const float* gbase = grid_buf + (size_t)bg * PLANE * 2;
    float* ob = out + (size_t)(b * 256 + c4) * PLANE;

    #pragma unroll 2
    for (int r = 0; r < 18; ++r) {
        const int idx = r * 2048 + tid * 2;        // 2 consecutive positions
        float4 g = *(const float4*)(gbase + (size_t)idx * 2);  // gx0,gy0,gx1,gy1
        float4 r0, r1;
        {   // position 0
            float x0f = floorf(g.x), y0f = floorf(g.y);
            float wx = g.x - x0f, wy = g.y - y0f;
            int base = (int)fmaf(y0f, 96.0f, x0f);
            float4 a0 = pl[base],      a1 = pl[base + 1];
            float4 b0 = pl[base + 96], b1 = pl[base + 97];
            float tx, bx;
            tx = a0.x + (a1.x - a0.x) * wx; bx = b0.x + (b1.x - b0.x) * wx; r0.x = tx + (bx - tx) * wy;
            tx = a0.y + (a1.y - a0.y) * wx; bx = b0.y + (b1.y - b0.y) * wx; r0.y = tx + (bx - tx) * wy;
            tx = a0.z + (a1.z - a0.z) * wx; bx = b0.z + (b1.z - b0.z) * wx; r0.z = tx + (bx - tx) * wy;
            tx = a0.w + (a1.w - a0.w) * wx; bx = b0.w + (b1.w - b0.w) * wx; r0.w = tx + (bx - tx) * wy;
        }
        {   // position 1
            float x0f = floorf(g.z), y0f = floorf(g.w);
            float wx = g.z - x0f, wy = g.w - y0f;
            int base = (int)fmaf(y0f, 96.0f, x0f);
            float4 a0 = pl[base],      a1 = pl[base + 1];
            float4 b0 = pl[base + 96], b1 = pl[base + 97];
            float tx, bx;
            tx = a0.x + (a1.x - a0.x) * wx; bx = b0.x + (b1.x - b0.x) * wx; r1.x = tx + (bx - tx) * wy;
            tx = a0.y + (a1.y - a0.y) * wx; bx = b0.y + (b1.y - b0.y) * wx; r1.y = tx + (bx - tx) * wy;
            tx = a0.z + (a1.z - a0.z) * wx; bx = b0.z + (b1.z - b0.z) * wx; r1.z = tx + (bx - tx) * wy;
            tx = a0.w + (a1.w - a0.w) * wx; bx = b0.w + (b1.w - b0.w) * wx; r1.w = tx + (bx - tx) * wy;
        }
        f32x2 s0 = {r0.x, r1.x};
        f32x2 s1 = {r0.y, r1.y};
        f32x2 s2 = {r0.z, r1.z};
        f32x2 s3 = {r0.w, r1.w};
        __builtin_nontemporal_store(s0, (f32x2*)(ob + idx));
        __builtin_nontemporal_store(s1, (f32x2*)(ob + PLANE + idx));
        __builtin_nontemporal_store(s2, (f32x2*)(ob + 2 * PLANE + idx));
        __builtin_nontemporal_store(s3, (f32x2*)(ob + 3 * PLANE + idx));
    }
}

extern "C" void kernel_launch(void* const* d_in, const int* in_sizes, int n_in,
                              void* d_out, int out_size, void* d_ws, size_t ws_size,
                              hipStream_t stream) {
    const float* x    = (const float*)d_in[0];
    const float* w    = (const float*)d_in[1];
    const float* bias = (const float*)d_in[2];
    float* out        = (float*)d_out;
    float* wt         = (float*)d_ws;                 // 32 KB transposed weights
    float* grid_buf   = wt + WT_FLOATS;               // 9.4 MB grid coords

    transpose_w_kernel<<<32, 256, 0, stream>>>(w, wt);
    conv_offset_kernel<<<1152, 256, 0, stream>>>(x, wt, bias, grid_buf);
    sample_kernel<<<512, 1024, 0, stream>>>(x, grid_buf, out);
}